// Round 2
// baseline (141.134 us; speedup 1.0000x reference)
//
#include <hip/hip_runtime.h>
#include <hip/hip_bf16.h>

// Problem constants
#define B_   4
#define N_   160
#define D_   64
#define ZI_  64
#define H1_  128
#define H2_  64
#define L_   4
#define LE_  8

typedef __bf16 bf16x8 __attribute__((ext_vector_type(8)));
typedef float  f32x4  __attribute__((ext_vector_type(4)));

// ---------------------------------------------------------------------------
// Stage A: per-(b,i) precompute (fp32 into workspace). All inputs fp32.
//   ui[b,i,h]   = (ne[b,i] @ Wi1[:64])[h] + (z_intra[b] @ Wi1[128:192])[h] + bi1[h]
//   pj[b,j,h]   = (ne[b,j] @ Wi1[64:128])[h]
//   qj[b,j,h]   = (ne[b,j] @ Wl1[64:128])[h]
//   uq[b,l,i,h] = (ne[b,i] @ Wl1[:64])[h] + (z_inter[b] @ Wl1[128:192])[h]
//                 + (lag[l] @ Wl1[192:200])[h] + bl1[h]
// grid = B*N blocks, 128 threads (h)
// ---------------------------------------------------------------------------
__global__ __launch_bounds__(128) void stage_a(
    const float* __restrict__ ne,
    const float* __restrict__ zi,
    const float* __restrict__ ze,
    const float* __restrict__ lag,
    const float* __restrict__ Wi1,
    const float* __restrict__ bi1,
    const float* __restrict__ Wl1,
    const float* __restrict__ bl1,
    float* __restrict__ ui, float* __restrict__ pj,
    float* __restrict__ qj, float* __restrict__ uq)
{
    const int bi = blockIdx.x;       // b*N + i
    const int b  = bi / N_;
    const int h  = threadIdx.x;      // 0..127

    const float* nerow = ne + bi * D_;

    float pi_ = 0.f, pj_ = 0.f, qi_ = 0.f, qj_ = 0.f;
#pragma unroll 8
    for (int d = 0; d < D_; ++d) {
        const float a = nerow[d];
        pi_ += a * Wi1[d * H1_ + h];
        pj_ += a * Wi1[(D_ + d) * H1_ + h];
        qi_ += a * Wl1[d * H1_ + h];
        qj_ += a * Wl1[(D_ + d) * H1_ + h];
    }
    float pz = 0.f, qz = 0.f;
#pragma unroll 8
    for (int z = 0; z < ZI_; ++z) {
        pz += zi[b * ZI_ + z] * Wi1[(2 * D_ + z) * H1_ + h];
        qz += ze[b * ZI_ + z] * Wl1[(2 * D_ + z) * H1_ + h];
    }

    ui[bi * H1_ + h] = pi_ + pz + bi1[h];
    pj[bi * H1_ + h] = pj_;
    qj[bi * H1_ + h] = qj_;

    const float qbase = qi_ + qz + bl1[h];
#pragma unroll
    for (int l = 0; l < L_; ++l) {
        float ql = 0.f;
#pragma unroll
        for (int e = 0; e < LE_; ++e)
            ql += lag[l * LE_ + e] * Wl1[(2 * D_ + ZI_ + e) * H1_ + h];
        uq[((b * L_ + l) * N_ + (bi % N_)) * H1_ + h] = qbase + ql;
    }
}

// ---------------------------------------------------------------------------
// Stage B: fused pairwise MLP via MFMA.
// One wave per (b,i) [intra, first B*N waves] or (b,l,i) [inter], 10 j-tiles
// of 16 each. Per tile: V[16x128] = relu(u + vj) built directly in A-fragment
// layout (bf16), H2pre = V @ W2 via 16x mfma_f32_16x16x32_bf16, epilogue:
// relu(H2pre + b2) . w3 (+b3) -> sigmoid -> mask -> fp32 store.
//
// MFMA 16x16x32 layouts (gfx950, HW-verified):
//   A: lane holds A[m = lane&15][k = 8*(lane>>4) + j], j=0..7
//   B: lane holds B[k = 8*(lane>>4) + j][n = lane&15]
//   C/D: lane holds D[row = 4*(lane>>4) + reg][col = lane&15]
// grid = 800 blocks x 256 threads = 3200 waves = 640 intra + 2560 inter
// ---------------------------------------------------------------------------
__global__ __launch_bounds__(256) void stage_b(
    const float* __restrict__ ui, const float* __restrict__ pj,
    const float* __restrict__ qj, const float* __restrict__ uq,
    const float* __restrict__ Wi2, const float* __restrict__ bi2,
    const float* __restrict__ Wi3, const float* __restrict__ bi3,
    const float* __restrict__ Wl2, const float* __restrict__ bl2,
    const float* __restrict__ Wl3, const float* __restrict__ bl3,
    float* __restrict__ out)
{
    const int wave = blockIdx.x * 4 + (threadIdx.x >> 6);
    const int lane = threadIdx.x & 63;
    const int q = lane >> 4;     // quad 0..3
    const int c = lane & 15;     // col-in-16

    const float* ubase;
    const float* vjbase;
    const float *W2, *b2, *w3;
    float b3f;
    long  obase;
    int   i;

    if (wave < B_ * N_) {                      // intra: W_t
        const int b = wave / N_;
        i = wave % N_;
        ubase  = ui + wave * H1_;
        vjbase = pj + b * N_ * H1_;
        W2 = Wi2; b2 = bi2; w3 = Wi3; b3f = bi3[0];
        obase = (long)wave * N_;
    } else {                                   // inter: A_lags_t
        const int w2i = wave - B_ * N_;        // = b*(L*N) + l*N + i
        const int b = w2i / (L_ * N_);
        i = w2i % N_;
        ubase  = uq + w2i * H1_;
        vjbase = qj + b * N_ * H1_;
        W2 = Wl2; b2 = bl2; w3 = Wl3; b3f = bl3[0];
        obase = (long)B_ * N_ * N_ + (long)w2i * N_;
    }

    // B fragments of W2 (128x64, row-major fp32 -> bf16), register-resident.
    bf16x8 bf[4][4];
#pragma unroll
    for (int kt = 0; kt < 4; ++kt)
#pragma unroll
        for (int ct = 0; ct < 4; ++ct) {
            bf16x8 t;
#pragma unroll
            for (int j = 0; j < 8; ++j)
                t[j] = (__bf16)W2[(32 * kt + 8 * q + j) * H2_ + 16 * ct + c];
            bf[kt][ct] = t;
        }

    // u slices for this lane's quad (row-invariant across the tile).
    f32x4 u0[4], u1[4];
#pragma unroll
    for (int kt = 0; kt < 4; ++kt) {
        const float* up = ubase + 32 * kt + 8 * q;
        u0[kt] = *(const f32x4*)(up);
        u1[kt] = *(const f32x4*)(up + 4);
    }

    float b2c[4], w3c[4];
#pragma unroll
    for (int ct = 0; ct < 4; ++ct) {
        b2c[ct] = b2[16 * ct + c];
        w3c[ct] = w3[16 * ct + c];
    }

    for (int jt = 0; jt < 10; ++jt) {
        const int j0 = jt * 16;
        f32x4 acc[4];
#pragma unroll
        for (int ct = 0; ct < 4; ++ct) acc[ct] = (f32x4)0.0f;

#pragma unroll
        for (int kt = 0; kt < 4; ++kt) {
            const float* vp = vjbase + (j0 + c) * H1_ + 32 * kt + 8 * q;
            const f32x4 v0 = *(const f32x4*)(vp);
            const f32x4 v1 = *(const f32x4*)(vp + 4);
            const f32x4 x0 = u0[kt] + v0;
            const f32x4 x1 = u1[kt] + v1;
            bf16x8 a;
            a[0] = (__bf16)fmaxf(x0[0], 0.f);
            a[1] = (__bf16)fmaxf(x0[1], 0.f);
            a[2] = (__bf16)fmaxf(x0[2], 0.f);
            a[3] = (__bf16)fmaxf(x0[3], 0.f);
            a[4] = (__bf16)fmaxf(x1[0], 0.f);
            a[5] = (__bf16)fmaxf(x1[1], 0.f);
            a[6] = (__bf16)fmaxf(x1[2], 0.f);
            a[7] = (__bf16)fmaxf(x1[3], 0.f);
#pragma unroll
            for (int ct = 0; ct < 4; ++ct)
                acc[ct] = __builtin_amdgcn_mfma_f32_16x16x32_bf16(
                    a, bf[kt][ct], acc[ct], 0, 0, 0);
        }

        // Epilogue: logit[row] = b3 + sum_col relu(H2pre + b2[col]) * w3[col]
        float logit[4];
#pragma unroll
        for (int r = 0; r < 4; ++r) {
            float p = 0.f;
#pragma unroll
            for (int ct = 0; ct < 4; ++ct) {
                const float h2 = fmaxf(acc[ct][r] + b2c[ct], 0.f);
                p += h2 * w3c[ct];
            }
            p += __shfl_xor(p, 1);
            p += __shfl_xor(p, 2);
            p += __shfl_xor(p, 4);
            p += __shfl_xor(p, 8);
            logit[r] = p;
        }

        if (c < 4) {
            const int row = 4 * q + c;   // row within tile, via logit[c]
            const int j = j0 + row;
            const float lg = logit[c] + b3f;
            const float s = (j == i) ? 0.f : 1.f / (1.f + __expf(-lg));
            out[obase + j] = s;
        }
    }
}

// ---------------------------------------------------------------------------
extern "C" void kernel_launch(void* const* d_in, const int* in_sizes, int n_in,
                              void* d_out, int out_size, void* d_ws, size_t ws_size,
                              hipStream_t stream) {
    const float* ne  = (const float*)d_in[0];
    const float* zi  = (const float*)d_in[1];
    const float* ze  = (const float*)d_in[2];
    const float* lag = (const float*)d_in[3];
    const float* Wi1 = (const float*)d_in[4];
    const float* bi1 = (const float*)d_in[5];
    const float* Wi2 = (const float*)d_in[6];
    const float* bi2 = (const float*)d_in[7];
    const float* Wi3 = (const float*)d_in[8];
    const float* bi3 = (const float*)d_in[9];
    const float* Wl1 = (const float*)d_in[10];
    const float* bl1 = (const float*)d_in[11];
    const float* Wl2 = (const float*)d_in[12];
    const float* bl2 = (const float*)d_in[13];
    const float* Wl3 = (const float*)d_in[14];
    const float* bl3 = (const float*)d_in[15];

    float* ws  = (float*)d_ws;
    float* ui  = ws;                       // B*N*H1     = 81920
    float* pjw = ws + 81920;               // B*N*H1     = 81920
    float* qjw = ws + 163840;              // B*N*H1     = 81920
    float* uqw = ws + 245760;              // B*L*N*H1   = 327680

    stage_a<<<B_ * N_, 128, 0, stream>>>(ne, zi, ze, lag, Wi1, bi1, Wl1, bl1,
                                         ui, pjw, qjw, uqw);

    stage_b<<<(B_ * N_ + B_ * L_ * N_) / 4, 256, 0, stream>>>(
        ui, pjw, qjw, uqw,
        Wi2, bi2, Wi3, bi3, Wl2, bl2, Wl3, bl3,
        (float*)d_out);
}

// Round 3
// 116.795 us; speedup vs baseline: 1.2084x; 1.2084x over previous
//
#include <hip/hip_runtime.h>
#include <hip/hip_bf16.h>

// Problem constants
#define B_   4
#define N_   160
#define D_   64
#define ZI_  64
#define H1_  128
#define H2_  64
#define L_   4
#define LE_  8

typedef __bf16 bf16x8 __attribute__((ext_vector_type(8)));
typedef float  f32x4  __attribute__((ext_vector_type(4)));

// ---------------------------------------------------------------------------
// Stage A: per-(b,i) precompute. fp32 u-rows + bf16 v-panels into workspace.
//   ui[b,i,h]   = ne[b,i]@Wi1[:64] + z_intra[b]@Wi1[128:192] + bi1      (fp32)
//   uq[b,l,i,h] = ne[b,i]@Wl1[:64] + z_inter[b]@Wl1[128:192] + lag[l]@Wl1[192:200] + bl1
//   vpi[b,j,h]  = bf16( ne[b,j]@Wi1[64:128] )
//   vpl[b,j,h]  = bf16( ne[b,j]@Wl1[64:128] )
// grid = B*N blocks, 128 threads (h)
// ---------------------------------------------------------------------------
__global__ __launch_bounds__(128) void stage_a(
    const float* __restrict__ ne,
    const float* __restrict__ zi,
    const float* __restrict__ ze,
    const float* __restrict__ lag,
    const float* __restrict__ Wi1,
    const float* __restrict__ bi1,
    const float* __restrict__ Wl1,
    const float* __restrict__ bl1,
    float* __restrict__ ui, float* __restrict__ uq,
    __bf16* __restrict__ vpi, __bf16* __restrict__ vpl)
{
    const int bi = blockIdx.x;       // b*N + i
    const int b  = bi / N_;
    const int h  = threadIdx.x;      // 0..127

    const float* nerow = ne + bi * D_;

    float pi_ = 0.f, pj_ = 0.f, qi_ = 0.f, qj_ = 0.f;
#pragma unroll 16
    for (int d = 0; d < D_; ++d) {
        const float a = nerow[d];
        pi_ += a * Wi1[d * H1_ + h];
        pj_ += a * Wi1[(D_ + d) * H1_ + h];
        qi_ += a * Wl1[d * H1_ + h];
        qj_ += a * Wl1[(D_ + d) * H1_ + h];
    }
    float pz = 0.f, qz = 0.f;
#pragma unroll 16
    for (int z = 0; z < ZI_; ++z) {
        pz += zi[b * ZI_ + z] * Wi1[(2 * D_ + z) * H1_ + h];
        qz += ze[b * ZI_ + z] * Wl1[(2 * D_ + z) * H1_ + h];
    }

    ui[bi * H1_ + h]  = pi_ + pz + bi1[h];
    vpi[bi * H1_ + h] = (__bf16)pj_;
    vpl[bi * H1_ + h] = (__bf16)qj_;

    const float qbase = qi_ + qz + bl1[h];
#pragma unroll
    for (int l = 0; l < L_; ++l) {
        float ql = 0.f;
#pragma unroll
        for (int e = 0; e < LE_; ++e)
            ql += lag[l * LE_ + e] * Wl1[(2 * D_ + ZI_ + e) * H1_ + h];
        uq[((b * L_ + l) * N_ + (bi % N_)) * H1_ + h] = qbase + ql;
    }
}

// ---------------------------------------------------------------------------
// Stage B: fused pairwise MLP via MFMA, j-panel staged in LDS per block.
// Block = 4 waves = 4 consecutive row-ids, always same batch/branch
// (boundaries at 160/640 are multiples of 4). Each wave: one (b,i) or
// (b,l,i), 10 j-tiles of 16. Panel is bf16 160x128 in LDS with XOR swizzle
// granule' = granule ^ (row&7) (16B granules) -> conflict-free writes+reads,
// 40960 B LDS -> exactly 4 blocks/CU (160 KB), 16 waves/CU.
//
// MFMA 16x16x32 layouts (gfx950, HW-verified):
//   A: lane holds A[m = lane&15][k = 8*(lane>>4) + j], j=0..7
//   B: lane holds B[k = 8*(lane>>4) + j][n = lane&15]
//   C/D: lane holds D[row = 4*(lane>>4) + reg][col = lane&15]
// ---------------------------------------------------------------------------
__global__ __launch_bounds__(256) void stage_b(
    const float* __restrict__ ui, const float* __restrict__ uq,
    const __bf16* __restrict__ vpi, const __bf16* __restrict__ vpl,
    const float* __restrict__ Wi2, const float* __restrict__ bi2,
    const float* __restrict__ Wi3, const float* __restrict__ bi3,
    const float* __restrict__ Wl2, const float* __restrict__ bl2,
    const float* __restrict__ Wl3, const float* __restrict__ bl3,
    float* __restrict__ out)
{
    __shared__ __bf16 panel[N_ * H1_];   // 40960 B, swizzled

    const int t    = threadIdx.x;        // 0..255
    const int wid  = t >> 6;
    const int lane = t & 63;
    const int q = lane >> 4;             // quad 0..3
    const int c = lane & 15;             // col-in-16

    const int blk  = blockIdx.x;         // 0..799
    const int wave = blk * 4 + wid;

    // Block-uniform panel source (all 4 waves share b and branch).
    const __bf16* psrc;
    if (blk < 160) psrc = vpi + (blk / 40) * (N_ * H1_);
    else           psrc = vpl + ((blk - 160) / 160) * (N_ * H1_);

    // Wave-specific row params.
    const float* ubase;
    const float *W2, *b2, *w3;
    float b3f;
    long  obase;
    int   i;
    if (wave < B_ * N_) {                      // intra: W_t
        i = wave % N_;
        ubase = ui + wave * H1_;
        W2 = Wi2; b2 = bi2; w3 = Wi3; b3f = bi3[0];
        obase = (long)wave * N_;
    } else {                                   // inter: A_lags_t
        const int w2i = wave - B_ * N_;        // b*(L*N) + l*N + i
        i = w2i % N_;
        ubase = uq + w2i * H1_;
        W2 = Wl2; b2 = bl2; w3 = Wl3; b3f = bl3[0];
        obase = (long)B_ * N_ * N_ + (long)w2i * N_;
    }

    // 1) Issue panel global loads first (coalesced 16B per thread x 10).
    bf16x8 stg[10];
#pragma unroll
    for (int it = 0; it < 10; ++it)
        stg[it] = *(const bf16x8*)(psrc + 2048 * it + 8 * t);

    // 2) Register loads that overlap the panel loads in flight.
    bf16x8 bfr[4][4];                    // W2 B-fragments (fp32 -> bf16)
#pragma unroll
    for (int kt = 0; kt < 4; ++kt)
#pragma unroll
        for (int ct = 0; ct < 4; ++ct) {
            bf16x8 tt;
#pragma unroll
            for (int j = 0; j < 8; ++j)
                tt[j] = (__bf16)W2[(32 * kt + 8 * q + j) * H2_ + 16 * ct + c];
            bfr[kt][ct] = tt;
        }

    f32x4 u0[4], u1[4];                  // u slices (row-invariant)
#pragma unroll
    for (int kt = 0; kt < 4; ++kt) {
        const float* up = ubase + 32 * kt + 8 * q;
        u0[kt] = *(const f32x4*)(up);
        u1[kt] = *(const f32x4*)(up + 4);
    }

    float b2c[4], w3c[4];
#pragma unroll
    for (int ct = 0; ct < 4; ++ct) {
        b2c[ct] = b2[16 * ct + c];
        w3c[ct] = w3[16 * ct + c];
    }

    // 3) Swizzled LDS write: thread t, iter it -> row = 16*it + (t>>4),
    //    granule g = t&15 stored at g ^ (row&7) = g ^ ((t>>4)&7).
    {
        const int gsw = (t & 15) ^ ((t >> 4) & 7);
        const int rowbase = (t >> 4) * H1_ + gsw * 8;
#pragma unroll
        for (int it = 0; it < 10; ++it)
            *(bf16x8*)(panel + 16 * it * H1_ + rowbase) = stg[it];
    }
    __syncthreads();

    // 4) Tile loop: everything from LDS/registers.
    for (int jt = 0; jt < 10; ++jt) {
        const __bf16* prow = panel + (16 * jt + c) * H1_;
        f32x4 acc[4];
#pragma unroll
        for (int ct = 0; ct < 4; ++ct) acc[ct] = (f32x4)0.0f;

#pragma unroll
        for (int kt = 0; kt < 4; ++kt) {
            // granule g = 4*kt + q, swizzled by row (16*jt+c)&7 = c&7
            const bf16x8 vb = *(const bf16x8*)(prow + (((4 * kt + q) ^ (c & 7)) << 3));
            bf16x8 a;
#pragma unroll
            for (int j = 0; j < 4; ++j) {
                a[j]     = (__bf16)fmaxf(u0[kt][j] + (float)vb[j],     0.f);
                a[4 + j] = (__bf16)fmaxf(u1[kt][j] + (float)vb[4 + j], 0.f);
            }
#pragma unroll
            for (int ct = 0; ct < 4; ++ct)
                acc[ct] = __builtin_amdgcn_mfma_f32_16x16x32_bf16(
                    a, bfr[kt][ct], acc[ct], 0, 0, 0);
        }

        // Epilogue: logit[r] = b3 + sum_col relu(H2pre + b2) * w3
        float logit[4];
#pragma unroll
        for (int r = 0; r < 4; ++r) {
            float p = 0.f;
#pragma unroll
            for (int ct = 0; ct < 4; ++ct) {
                const float h2 = fmaxf(acc[ct][r] + b2c[ct], 0.f);
                p += h2 * w3c[ct];
            }
            p += __shfl_xor(p, 1);
            p += __shfl_xor(p, 2);
            p += __shfl_xor(p, 4);
            p += __shfl_xor(p, 8);
            logit[r] = p;
        }

        if (c < 4) {
            const int j = 16 * jt + 4 * q + c;
            const float lg = logit[c] + b3f;
            const float s = (j == i) ? 0.f : 1.f / (1.f + __expf(-lg));
            out[obase + j] = s;
        }
    }
}

// ---------------------------------------------------------------------------
extern "C" void kernel_launch(void* const* d_in, const int* in_sizes, int n_in,
                              void* d_out, int out_size, void* d_ws, size_t ws_size,
                              hipStream_t stream) {
    const float* ne  = (const float*)d_in[0];
    const float* zi  = (const float*)d_in[1];
    const float* ze  = (const float*)d_in[2];
    const float* lag = (const float*)d_in[3];
    const float* Wi1 = (const float*)d_in[4];
    const float* bi1 = (const float*)d_in[5];
    const float* Wi2 = (const float*)d_in[6];
    const float* bi2 = (const float*)d_in[7];
    const float* Wi3 = (const float*)d_in[8];
    const float* bi3 = (const float*)d_in[9];
    const float* Wl1 = (const float*)d_in[10];
    const float* bl1 = (const float*)d_in[11];
    const float* Wl2 = (const float*)d_in[12];
    const float* bl2 = (const float*)d_in[13];
    const float* Wl3 = (const float*)d_in[14];
    const float* bl3 = (const float*)d_in[15];

    float*  ws  = (float*)d_ws;
    float*  ui  = ws;                          // 640*128 fp32
    float*  uqw = ws + 81920;                  // 2560*128 fp32
    __bf16* vpi = (__bf16*)(ws + 409600);      // 640*128 bf16 (16B-aligned)
    __bf16* vpl = vpi + 81920;                 // 640*128 bf16

    stage_a<<<B_ * N_, 128, 0, stream>>>(ne, zi, ze, lag, Wi1, bi1, Wl1, bl1,
                                         ui, uqw, vpi, vpl);

    stage_b<<<(B_ * N_ + B_ * L_ * N_) / 4, 256, 0, stream>>>(
        ui, uqw, vpi, vpl,
        Wi2, bi2, Wi3, bi3, Wl2, bl2, Wl3, bl3,
        (float*)d_out);
}